// Round 1
// baseline (1889.382 us; speedup 1.0000x reference)
//
#include <hip/hip_runtime.h>
#include <hip/hip_bf16.h>

#define B_   128
#define L_   512
#define E_   512
#define H_   256
#define K_   64
#define G4H  1024   // 4*H
#define LOG2E 1.4426950408889634f

typedef __bf16 bf16x8 __attribute__((ext_vector_type(8)));
typedef float  f32x4  __attribute__((ext_vector_type(4)));
typedef int    i32x8  __attribute__((ext_vector_type(8)));
typedef unsigned short u16x8 __attribute__((ext_vector_type(8)));

__device__ inline unsigned short f2bf(float f) {
    unsigned int x = __builtin_bit_cast(unsigned int, f);
    unsigned int r = (x + 0x7fffu + ((x >> 16) & 1u)) >> 16;
    return (unsigned short)r;
}
__device__ inline float bf2f(unsigned short u) {
    unsigned int x = ((unsigned int)u) << 16;
    return __builtin_bit_cast(float, x);
}
__device__ inline unsigned int pack2(float lo, float hi) {
    return (unsigned int)f2bf(lo) | ((unsigned int)f2bf(hi) << 16);
}
__device__ inline float ex2(float x) { return __builtin_amdgcn_exp2f(x); }
__device__ inline float rcp_(float x) { return __builtin_amdgcn_rcpf(x); }

// async global->LDS, 16B per lane; LDS dest must be wave-uniform + lane*16
__device__ inline void gl_lds16(const unsigned short* g, unsigned short* l) {
    __builtin_amdgcn_global_load_lds(
        (const __attribute__((address_space(1))) unsigned int*)g,
        (__attribute__((address_space(3))) unsigned int*)l, 16, 0, 0);
}

// ---------------------------------------------------------------------------
// Setup: whh -> fp8 e4m3 scaled by LOG2E; w_emit -> bf16;
// w_ih -> bf16 * LOG2E with gate-interleaved row perm wp[n'=col*4+gate];
// bias_p = (b_ih + b_hh) * LOG2E, permuted.
// ---------------------------------------------------------------------------
__global__ void setup_convert(const float* __restrict__ whh_f, const float* __restrict__ whh_b,
                              const float* __restrict__ wemit,
                              const float* __restrict__ wihf, const float* __restrict__ wihb,
                              const float* __restrict__ bihf, const float* __restrict__ bhhf,
                              const float* __restrict__ bihb, const float* __restrict__ bhhb,
                              unsigned char* __restrict__ whh8,
                              unsigned short* __restrict__ wemit_bf,
                              unsigned short* __restrict__ wp,
                              float* __restrict__ bias_p) {
    int i = blockIdx.x * 256 + threadIdx.x;       // grid 1024*256 = 262144
    if (i < 262144) {
        int j = 2 * i;
        float v0 = (j < 262144) ? whh_f[j] : whh_b[j - 262144];
        float v1 = (j + 1 < 262144) ? whh_f[j + 1] : whh_b[j + 1 - 262144];
        int pk = __builtin_amdgcn_cvt_pk_fp8_f32(v0 * LOG2E, v1 * LOG2E, 0, false);
        ((unsigned short*)whh8)[i] = (unsigned short)(pk & 0xffff);
    }
    if (i < K_ * 2 * H_) wemit_bf[i] = f2bf(wemit[i]);
    if (i < 131072) {
        int rp = i >> 6;            // permuted row 0..2047
        int k8 = (i & 63) * 8;
        int dd = rp >> 10, np = rp & 1023;
        int srow = (np & 3) * 256 + (np >> 2);
        const float* src = (dd == 0 ? wihf : wihb) + (size_t)srow * 512 + k8;
        float4 a  = *reinterpret_cast<const float4*>(src);
        float4 b2 = *reinterpret_cast<const float4*>(src + 4);
        uint4 pk = { pack2(a.x * LOG2E, a.y * LOG2E), pack2(a.z * LOG2E, a.w * LOG2E),
                     pack2(b2.x * LOG2E, b2.y * LOG2E), pack2(b2.z * LOG2E, b2.w * LOG2E) };
        *reinterpret_cast<uint4*>(wp + (size_t)rp * 512 + k8) = pk;
    }
    if (i < 2048) {
        int dd = i >> 10, np = i & 1023;
        int srow = (np & 3) * 256 + (np >> 2);
        bias_p[i] = ((dd == 0) ? (bihf[srow] + bhhf[srow]) : (bihb[srow] + bhhb[srow])) * LOG2E;
    }
}

// x (B,L,E) fp32 -> bf16, same layout
__global__ void convert_x(const float* __restrict__ x, unsigned short* __restrict__ xb) {
    int i = blockIdx.x * 256 + threadIdx.x;     // 16384 blocks
    float4 a = reinterpret_cast<const float4*>(x)[i * 2];
    float4 b = reinterpret_cast<const float4*>(x)[i * 2 + 1];
    uint4 p = { pack2(a.x, a.y), pack2(a.z, a.w), pack2(b.x, b.y), pack2(b.z, b.w) };
    reinterpret_cast<uint4*>(xb)[i] = p;
}

// ---------------------------------------------------------------------------
// pre3[d][b][l][n'] (bf16, b-major), n' = col*4+gate, scaled by LOG2E.
// m97-style: 128x128 tile, BK=32, global_load_lds(16B). M-tile = one b, 128 l.
// ---------------------------------------------------------------------------
__global__ __launch_bounds__(256) void pre_gemm(
    const unsigned short* __restrict__ xb,    // (B,L,E) bf16
    const unsigned short* __restrict__ wp,    // (2048,512) bf16 permuted*LOG2E
    const float* __restrict__ bias_p,         // (2048) permuted*LOG2E
    unsigned short* __restrict__ pre3)        // [2][128][512][1024]
{
    __shared__ unsigned short A_lds[128 * 32];   // [row][k], 64B/row (no pad: DMA linear)
    __shared__ unsigned short B_lds[128 * 32];

    int nt = blockIdx.x, mt = blockIdx.y;
    int tid = threadIdx.x;
    int n0 = nt * 128;
    int b  = mt >> 2, l0 = (mt & 3) * 128;
    int w = tid >> 6, lane = tid & 63;
    int q = lane >> 4, ln = lane & 15;
    int wm = (w >> 1) * 64, wn = (w & 1) * 64;

    f32x4 acc[4][4];
    #pragma unroll
    for (int i = 0; i < 4; ++i)
        #pragma unroll
        for (int j = 0; j < 4; ++j) acc[i][j] = (f32x4){0.f, 0.f, 0.f, 0.f};

    int r_ = tid >> 2, kp = (tid & 3) * 8;
    const unsigned short* asrc0 = xb + ((size_t)b * 512 + l0 + r_) * 512 + kp;
    const unsigned short* asrc1 = asrc0 + (size_t)64 * 512;
    const unsigned short* bsrc0 = wp + (size_t)(n0 + r_) * 512 + kp;
    const unsigned short* bsrc1 = bsrc0 + (size_t)64 * 512;
    unsigned short* adst0 = &A_lds[tid * 8];
    unsigned short* adst1 = &A_lds[2048 + tid * 8];
    unsigned short* bdst0 = &B_lds[tid * 8];
    unsigned short* bdst1 = &B_lds[2048 + tid * 8];

    for (int kc = 0; kc < 16; ++kc) {
        int k0 = kc * 32;
        gl_lds16(asrc0 + k0, adst0);
        gl_lds16(asrc1 + k0, adst1);
        gl_lds16(bsrc0 + k0, bdst0);
        gl_lds16(bsrc1 + k0, bdst1);
        __syncthreads();   // drains vmcnt -> LDS filled

        bf16x8 af[4], bfv[4];
        #pragma unroll
        for (int ms = 0; ms < 4; ++ms)
            af[ms] = *reinterpret_cast<const bf16x8*>(&A_lds[(wm + ms * 16 + ln) * 32 + q * 8]);
        #pragma unroll
        for (int ns = 0; ns < 4; ++ns)
            bfv[ns] = *reinterpret_cast<const bf16x8*>(&B_lds[(wn + ns * 16 + ln) * 32 + q * 8]);
        #pragma unroll
        for (int ms = 0; ms < 4; ++ms)
            #pragma unroll
            for (int ns = 0; ns < 4; ++ns)
                acc[ms][ns] = __builtin_amdgcn_mfma_f32_16x16x32_bf16(af[ms], bfv[ns], acc[ms][ns], 0, 0, 0);
        __syncthreads();   // frag reads done before next DMA overwrites
    }

    #pragma unroll
    for (int ns = 0; ns < 4; ++ns) {
        int n = n0 + wn + ns * 16 + ln;
        float bias = bias_p[n];
        int dsel = n >> 10, np = n & 1023;
        #pragma unroll
        for (int ms = 0; ms < 4; ++ms) {
            #pragma unroll
            for (int rg = 0; rg < 4; ++rg) {
                int l = l0 + wm + ms * 16 + q * 4 + rg;
                pre3[(((size_t)dsel * 128 + b) * 512 + l) * 1024 + np] = f2bf(acc[ms][ns][rg] + bias);
            }
        }
    }
}

// ---------------------------------------------------------------------------
// LSTM scan v7: 16 WGs, SIXTEEN sequences per WG (all 16 M-rows of the MFMA
// valid -> 16x less wasted matrix-pipe work than v6's 1-seq/WG).
// Operand swap: A = W_hh row-tiles, B = h (16 seqs). Both frags have the
// identical lane layout ([idx=ln][k=q*32..]) so loads are unchanged; C now
// gives col=seq(=ln), row=n-within-tile(=q*4+rg). With tile T = g*16+(w+8s),
// each lane holds all 4 gates of 8 (seq,col) units directly in acc[g][s][rg]
// -> zero shuffles; h writeback packs 4 consecutive cols into one
// ds_write_b32; hcat packs into one 8B store. ONE barrier per step.
// ---------------------------------------------------------------------------
__global__ __launch_bounds__(512, 2) void lstm_scan(
    const unsigned short* __restrict__ pre3,  // [2][128][512][1024] bf16 (scaled)
    const unsigned char* __restrict__ whh8,   // [2][1024][256] fp8 e4m3 (scaled)
    unsigned short* __restrict__ hcat)        // [512][128][512] bf16
{
    __shared__ unsigned char h_lds[2][16 * 272];   // [seq][col], 272B row stride

    int wg = blockIdx.x;           // 16 = 2 dirs x 8 batch-groups
    int d = wg >> 3, b0 = (wg & 7) * 16;
    int tid = threadIdx.x, w = tid >> 6, lane = tid & 63;
    int q = lane >> 4, ln = lane & 15;

    const unsigned char* whh_d = whh8 + (size_t)d * (1024 * 256);

    // A-frags (weights): tile T = g*16 + (w+8s); lane ln holds W[n=T*16+ln][k=kc*128+q*32 ..+31]
    i32x8 wh[4][2][2];
    #pragma unroll
    for (int g = 0; g < 4; ++g)
        #pragma unroll
        for (int s = 0; s < 2; ++s) {
            int row = g * 256 + (w + 8 * s) * 16 + ln;
            #pragma unroll
            for (int kc = 0; kc < 2; ++kc)
                wh[g][s][kc] = *reinterpret_cast<const i32x8*>(
                    whh_d + (size_t)row * 256 + kc * 128 + q * 32);
        }

    for (int i = tid; i < (2 * 16 * 272) / 4; i += 512) ((int*)h_lds)[i] = 0;

    // per-lane sequence (= B-col = ln) and n' base offsets for its 8 units
    const unsigned short* pre_b = pre3 + (size_t)(d * 128 + b0 + ln) * (512 * 1024);
    int nof[2] = { (w * 16 + q * 4) * 4, ((w + 8) * 16 + q * 4) * 4 };

    // pre buffers: P[s][half] = 8 bf16; 16 shorts = gates (rg*4+g) for 4 cols
    u16x8 PA[2][2], PB[2][2];
    {
        int la  = d ? (L_ - 1) : 0;
        int lb_ = d ? (L_ - 2) : 1;
        #pragma unroll
        for (int s = 0; s < 2; ++s) {
            PA[s][0] = *reinterpret_cast<const u16x8*>(pre_b + (size_t)la  * 1024 + nof[s]);
            PA[s][1] = *reinterpret_cast<const u16x8*>(pre_b + (size_t)la  * 1024 + nof[s] + 8);
            PB[s][0] = *reinterpret_cast<const u16x8*>(pre_b + (size_t)lb_ * 1024 + nof[s]);
            PB[s][1] = *reinterpret_cast<const u16x8*>(pre_b + (size_t)lb_ * 1024 + nof[s] + 8);
        }
    }
    __syncthreads();

    float cst[2][4];
    #pragma unroll
    for (int s = 0; s < 2; ++s)
        #pragma unroll
        for (int rg = 0; rg < 4; ++rg) cst[s][rg] = 0.f;

    auto step_fn = [&](int t, u16x8 (&P)[2][2], int t2) {
        int p = t & 1;
        int l = d ? (L_ - 1 - t) : t;

        // ---- B-frags: h of the 16 seqs (lane ln = seq ln), k = kc*128+q*32 ----
        i32x8 af0, af1;
        {
            const unsigned char* ab = &h_lds[p][ln * 272 + q * 32];
            uint4 a0 = *reinterpret_cast<const uint4*>(ab);
            uint4 a1 = *reinterpret_cast<const uint4*>(ab + 16);
            af0 = (i32x8){ (int)a0.x, (int)a0.y, (int)a0.z, (int)a0.w,
                           (int)a1.x, (int)a1.y, (int)a1.z, (int)a1.w };
            uint4 b0v = *reinterpret_cast<const uint4*>(ab + 128);
            uint4 b1v = *reinterpret_cast<const uint4*>(ab + 144);
            af1 = (i32x8){ (int)b0v.x, (int)b0v.y, (int)b0v.z, (int)b0v.w,
                           (int)b1v.x, (int)b1v.y, (int)b1v.z, (int)b1v.w };
        }

        // ---- MFMA: G^T tiles, A=W rows, B=h. acc[g][s]: row=q*4+rg -> col
        //      offset within tile, col=ln -> seq ----
        f32x4 acc[4][2];
        #pragma unroll
        for (int g = 0; g < 4; ++g) {
            acc[g][0] = (f32x4){0.f, 0.f, 0.f, 0.f};
            acc[g][1] = (f32x4){0.f, 0.f, 0.f, 0.f};
        }
        #pragma unroll
        for (int g = 0; g < 4; ++g)
            #pragma unroll
            for (int s = 0; s < 2; ++s) {
                acc[g][s] = __builtin_amdgcn_mfma_scale_f32_16x16x128_f8f6f4(
                    wh[g][s][0], af0, acc[g][s], 0, 0, 0, 0x7f7f7f7f, 0, 0x7f7f7f7f);
                acc[g][s] = __builtin_amdgcn_mfma_scale_f32_16x16x128_f8f6f4(
                    wh[g][s][1], af1, acc[g][s], 0, 0, 0, 0x7f7f7f7f, 0, 0x7f7f7f7f);
            }

        // ---- activation: 8 units/lane = (s, rg); all 4 gates in acc[g][s][rg] ----
        #pragma unroll
        for (int s = 0; s < 2; ++s) {
            float hv[4];
            #pragma unroll
            for (int rg = 0; rg < 4; ++rg) {
                float vi = acc[0][s][rg] + bf2f((unsigned short)P[s][rg >> 1][(rg & 1) * 4 + 0]);
                float vf = acc[1][s][rg] + bf2f((unsigned short)P[s][rg >> 1][(rg & 1) * 4 + 1]);
                float vg = acc[2][s][rg] + bf2f((unsigned short)P[s][rg >> 1][(rg & 1) * 4 + 2]);
                float vo = acc[3][s][rg] + bf2f((unsigned short)P[s][rg >> 1][(rg & 1) * 4 + 3]);
                float ei  = ex2(vi);
                float e2g = ex2(vg + vg);
                float itg = (ei * (e2g - 1.f)) * rcp_((1.f + ei) * (1.f + e2g)); // sigm(i)*tanh(g)
                float sf  = rcp_(1.f + ex2(-vf));
                float cn  = fmaf(sf, cst[s][rg], itg);
                cst[s][rg] = cn;
                float tc  = fmaf(-2.f, rcp_(1.f + ex2((2.f * LOG2E) * cn)), 1.f); // tanh(c)
                float so  = rcp_(1.f + ex2(-vo));
                hv[rg] = so * tc;
            }
            int colb = (w + 8 * s) * 16 + q * 4;
            unsigned int w0 = (unsigned int)__builtin_amdgcn_cvt_pk_fp8_f32(hv[0], hv[1], 0, false);
            unsigned int w1 = (unsigned int)__builtin_amdgcn_cvt_pk_fp8_f32(hv[2], hv[3], (int)w0, true);
            *reinterpret_cast<unsigned int*>(&h_lds[p ^ 1][ln * 272 + colb]) = w1;
            ushort4 hc = { f2bf(hv[0]), f2bf(hv[1]), f2bf(hv[2]), f2bf(hv[3]) };
            *reinterpret_cast<ushort4*>(
                hcat + ((size_t)l * 128 + b0 + ln) * 512 + d * 256 + colb) = hc;
        }

        // ---- prefetch pre[t+2] into the buffer just consumed ----
        int t2c = (t2 < L_ - 1) ? t2 : (L_ - 1);
        int l2 = d ? (L_ - 1 - t2c) : t2c;
        #pragma unroll
        for (int s = 0; s < 2; ++s) {
            P[s][0] = *reinterpret_cast<const u16x8*>(pre_b + (size_t)l2 * 1024 + nof[s]);
            P[s][1] = *reinterpret_cast<const u16x8*>(pre_b + (size_t)l2 * 1024 + nof[s] + 8);
        }
        __syncthreads();   // h_lds[p^1] complete for next step
    };

    for (int tt = 0; tt < L_; tt += 2) {
        step_fn(tt,     PA, tt + 2);
        step_fn(tt + 1, PB, tt + 3);
    }
}

// ---------------------------------------------------------------------------
// emit[b][l][k] = hcat[l][b][:] . w_emit[k][:] + b_emit[k]   (fp32 out)
// ---------------------------------------------------------------------------
__global__ __launch_bounds__(256) void emit_gemm(
    const unsigned short* __restrict__ hcat,   // [L*B][512]
    const unsigned short* __restrict__ wemit,  // [64][512]
    const float* __restrict__ bemit,           // [64]
    float* __restrict__ emit)                  // [B][L][64]
{
    int m0 = blockIdx.x * 64;
    int tid = threadIdx.x, w = tid >> 6, lane = tid & 63;
    int quad = lane >> 4, ln = lane & 15;
    int mrow = m0 + w * 16;

    f32x4 acc[4];
    #pragma unroll
    for (int i = 0; i < 4; ++i) acc[i] = (f32x4){0.f, 0.f, 0.f, 0.f};

    const unsigned short* arow = hcat + (size_t)(mrow + ln) * 512;
    #pragma unroll 4
    for (int kc = 0; kc < 16; ++kc) {
        bf16x8 af = *reinterpret_cast<const bf16x8*>(arow + kc * 32 + quad * 8);
        #pragma unroll
        for (int T = 0; T < 4; ++T) {
            bf16x8 bfv = *reinterpret_cast<const bf16x8*>(wemit + (size_t)(T * 16 + ln) * 512 + kc * 32 + quad * 8);
            acc[T] = __builtin_amdgcn_mfma_f32_16x16x32_bf16(af, bfv, acc[T], 0, 0, 0);
        }
    }
    #pragma unroll
    for (int T = 0; T < 4; ++T) {
        int k = T * 16 + ln;
        float bias = bemit[k];
        #pragma unroll
        for (int rg = 0; rg < 4; ++rg) {
            int m = mrow + quad * 4 + rg;
            int ll = m >> 7, bidx = m & 127;
            emit[((size_t)bidx * L_ + ll) * K_ + k] = acc[T][rg] + bias;
        }
    }
}

// ---------------------------------------------------------------------------
// CRF: per batch row, 511 sequential steps.
// r7: 4 independent fma accumulators (breaks the 64-deep serial chain),
// double-buffered els -> ONE barrier per step.
// ---------------------------------------------------------------------------
__global__ __launch_bounds__(64) void crf_kernel(
    const float* __restrict__ emit,    // [B][L][64]
    const int* __restrict__ labels,    // [B][L]
    const float* __restrict__ trans,   // [64][64]
    float* __restrict__ out)           // [B]
{
    __shared__ float els[2][64];
    int b = blockIdx.x, lane = threadIdx.x;
    const float* eb = emit + (size_t)b * L_ * K_;
    const int* lb = labels + (size_t)b * L_;

    float gold = 0.f;
    for (int t = lane; t < L_; t += 64) gold += eb[(size_t)t * K_ + lb[t]];
    for (int t = lane; t < L_ - 1; t += 64) gold += trans[lb[t] * K_ + lb[t + 1]];
    #pragma unroll
    for (int off = 32; off; off >>= 1) gold += __shfl_down(gold, off);

    float expT[64];   // column `lane` of exp(T)
    #pragma unroll
    for (int i = 0; i < 64; ++i) expT[i] = __expf(trans[i * K_ + lane]);

    float dstate = eb[lane];
    float enext = eb[K_ + lane];
    for (int t = 1; t < L_; ++t) {
        float ecur = enext;
        if (t + 1 < L_) enext = eb[(size_t)(t + 1) * K_ + lane];
        float M = __builtin_amdgcn_readfirstlane(dstate);   // cheap shared shift
        float e = __expf(dstate - M);
        float* el = els[t & 1];
        el[lane] = e;
        __syncthreads();
        float s0 = 0.f, s1 = 0.f, s2 = 0.f, s3 = 0.f;
        #pragma unroll
        for (int i = 0; i < 64; i += 16) {
            float4 a0 = *reinterpret_cast<const float4*>(&el[i]);
            float4 a1 = *reinterpret_cast<const float4*>(&el[i + 4]);
            float4 a2 = *reinterpret_cast<const float4*>(&el[i + 8]);
            float4 a3 = *reinterpret_cast<const float4*>(&el[i + 12]);
            s0 = fmaf(a0.x, expT[i], s0);      s0 = fmaf(a0.y, expT[i + 1], s0);
            s0 = fmaf(a0.z, expT[i + 2], s0);  s0 = fmaf(a0.w, expT[i + 3], s0);
            s1 = fmaf(a1.x, expT[i + 4], s1);  s1 = fmaf(a1.y, expT[i + 5], s1);
            s1 = fmaf(a1.z, expT[i + 6], s1);  s1 = fmaf(a1.w, expT[i + 7], s1);
            s2 = fmaf(a2.x, expT[i + 8], s2);  s2 = fmaf(a2.y, expT[i + 9], s2);
            s2 = fmaf(a2.z, expT[i + 10], s2); s2 = fmaf(a2.w, expT[i + 11], s2);
            s3 = fmaf(a3.x, expT[i + 12], s3); s3 = fmaf(a3.y, expT[i + 13], s3);
            s3 = fmaf(a3.z, expT[i + 14], s3); s3 = fmaf(a3.w, expT[i + 15], s3);
        }
        dstate = M + __logf((s0 + s1) + (s2 + s3)) + ecur;
    }
    float M = __builtin_amdgcn_readfirstlane(dstate);
    float e = __expf(dstate - M);
    float s = e;
    #pragma unroll
    for (int off = 32; off; off >>= 1) s += __shfl_xor(s, off);
    float logZ = M + __logf(s);
    if (lane == 0) out[b] = -(gold - logZ);
}

// ---------------------------------------------------------------------------
// Workspace layout (bytes). Overlays (disjoint lifetimes):
//   xb aliases hcat; emit aliases pre3 head.
// ---------------------------------------------------------------------------
#define OFF_PRE    ((size_t)0)                        // 268435456
#define OFF_EMIT   OFF_PRE                            // 16777216 (alias)
#define OFF_HCAT   ((size_t)268435456)                // 67108864
#define OFF_XB     OFF_HCAT                           // 67108864 (alias)
#define OFF_WHH8   ((size_t)(OFF_HCAT + 67108864))    // 524288
#define OFF_WEMIT  ((size_t)(OFF_WHH8 + 524288))      // 65536
#define OFF_WP     ((size_t)(OFF_WEMIT + 65536))      // 2097152
#define OFF_BIAS   ((size_t)(OFF_WP + 2097152))       // 8192

extern "C" void kernel_launch(void* const* d_in, const int* in_sizes, int n_in,
                              void* d_out, int out_size, void* d_ws, size_t ws_size,
                              hipStream_t stream) {
    const float* x      = (const float*)d_in[0];
    const int*   labels = (const int*)d_in[1];
    const float* wihf   = (const float*)d_in[2];
    const float* whhf   = (const float*)d_in[3];
    const float* bihf   = (const float*)d_in[4];
    const float* bhhf   = (const float*)d_in[5];
    const float* wihb   = (const float*)d_in[6];
    const float* whhb   = (const float*)d_in[7];
    const float* bihb   = (const float*)d_in[8];
    const float* bhhb   = (const float*)d_in[9];
    const float* wemit  = (const float*)d_in[10];
    const float* bemit  = (const float*)d_in[11];
    const float* trans  = (const float*)d_in[12];
    float* out = (float*)d_out;

    char* ws = (char*)d_ws;
    unsigned short* pre3   = (unsigned short*)(ws + OFF_PRE);
    unsigned short* hcat   = (unsigned short*)(ws + OFF_HCAT);
    unsigned short* xb     = (unsigned short*)(ws + OFF_XB);
    float*          emit   = (float*)(ws + OFF_EMIT);
    unsigned char*  whh8   = (unsigned char*)(ws + OFF_WHH8);
    unsigned short* we_bf  = (unsigned short*)(ws + OFF_WEMIT);
    unsigned short* wp     = (unsigned short*)(ws + OFF_WP);
    float*          bias_p = (float*)(ws + OFF_BIAS);

    setup_convert<<<1024, 256, 0, stream>>>(whhf, whhb, wemit, wihf, wihb,
                                            bihf, bhhf, bihb, bhhb,
                                            whh8, we_bf, wp, bias_p);
    convert_x<<<16384, 256, 0, stream>>>(x, xb);
    pre_gemm<<<dim3(16, 512), 256, 0, stream>>>(xb, wp, bias_p, pre3);
    lstm_scan<<<16, 512, 0, stream>>>(pre3, whh8, hcat);
    emit_gemm<<<1024, 256, 0, stream>>>(hcat, we_bf, bemit, emit);
    crf_kernel<<<128, 64, 0, stream>>>(emit, labels, trans, out);
}

// Round 2
// 1119.539 us; speedup vs baseline: 1.6876x; 1.6876x over previous
//
#include <hip/hip_runtime.h>
#include <hip/hip_bf16.h>

#define B_   128
#define L_   512
#define E_   512
#define H_   256
#define K_   64
#define G4H  1024   // 4*H
#define LOG2E 1.4426950408889634f

typedef __bf16 bf16x8 __attribute__((ext_vector_type(8)));
typedef float  f32x4  __attribute__((ext_vector_type(4)));
typedef int    i32x8  __attribute__((ext_vector_type(8)));

__device__ inline unsigned short f2bf(float f) {
    unsigned int x = __builtin_bit_cast(unsigned int, f);
    unsigned int r = (x + 0x7fffu + ((x >> 16) & 1u)) >> 16;
    return (unsigned short)r;
}
__device__ inline float bf2f(unsigned short u) {
    unsigned int x = ((unsigned int)u) << 16;
    return __builtin_bit_cast(float, x);
}
__device__ inline unsigned int pack2(float lo, float hi) {
    return (unsigned int)f2bf(lo) | ((unsigned int)f2bf(hi) << 16);
}
__device__ inline float ex2(float x) { return __builtin_amdgcn_exp2f(x); }
__device__ inline float rcp_(float x) { return __builtin_amdgcn_rcpf(x); }

// async global->LDS, 16B per lane; LDS dest must be wave-uniform + lane*16
__device__ inline void gl_lds16(const unsigned short* g, unsigned short* l) {
    __builtin_amdgcn_global_load_lds(
        (const __attribute__((address_space(1))) unsigned int*)g,
        (__attribute__((address_space(3))) unsigned int*)l, 16, 0, 0);
}

// ---------------------------------------------------------------------------
// Setup: whh -> fp8 e4m3 scaled by LOG2E; w_emit -> bf16;
// w_ih -> bf16 * LOG2E with gate-interleaved row perm wp[n'=col*4+gate];
// bias_p = (b_ih + b_hh) * LOG2E, permuted.
// ---------------------------------------------------------------------------
__global__ void setup_convert(const float* __restrict__ whh_f, const float* __restrict__ whh_b,
                              const float* __restrict__ wemit,
                              const float* __restrict__ wihf, const float* __restrict__ wihb,
                              const float* __restrict__ bihf, const float* __restrict__ bhhf,
                              const float* __restrict__ bihb, const float* __restrict__ bhhb,
                              unsigned char* __restrict__ whh8,
                              unsigned short* __restrict__ wemit_bf,
                              unsigned short* __restrict__ wp,
                              float* __restrict__ bias_p) {
    int i = blockIdx.x * 256 + threadIdx.x;       // grid 1024*256 = 262144
    if (i < 262144) {
        int j = 2 * i;
        float v0 = (j < 262144) ? whh_f[j] : whh_b[j - 262144];
        float v1 = (j + 1 < 262144) ? whh_f[j + 1] : whh_b[j + 1 - 262144];
        int pk = __builtin_amdgcn_cvt_pk_fp8_f32(v0 * LOG2E, v1 * LOG2E, 0, false);
        ((unsigned short*)whh8)[i] = (unsigned short)(pk & 0xffff);
    }
    if (i < K_ * 2 * H_) wemit_bf[i] = f2bf(wemit[i]);
    if (i < 131072) {
        int rp = i >> 6;            // permuted row 0..2047
        int k8 = (i & 63) * 8;
        int dd = rp >> 10, np = rp & 1023;
        int srow = (np & 3) * 256 + (np >> 2);
        const float* src = (dd == 0 ? wihf : wihb) + (size_t)srow * 512 + k8;
        float4 a  = *reinterpret_cast<const float4*>(src);
        float4 b2 = *reinterpret_cast<const float4*>(src + 4);
        uint4 pk = { pack2(a.x * LOG2E, a.y * LOG2E), pack2(a.z * LOG2E, a.w * LOG2E),
                     pack2(b2.x * LOG2E, b2.y * LOG2E), pack2(b2.z * LOG2E, b2.w * LOG2E) };
        *reinterpret_cast<uint4*>(wp + (size_t)rp * 512 + k8) = pk;
    }
    if (i < 2048) {
        int dd = i >> 10, np = i & 1023;
        int srow = (np & 3) * 256 + (np >> 2);
        bias_p[i] = ((dd == 0) ? (bihf[srow] + bhhf[srow]) : (bihb[srow] + bhhb[srow])) * LOG2E;
    }
}

// x (B,L,E) fp32 -> bf16, same layout
__global__ void convert_x(const float* __restrict__ x, unsigned short* __restrict__ xb) {
    int i = blockIdx.x * 256 + threadIdx.x;     // 16384 blocks
    float4 a = reinterpret_cast<const float4*>(x)[i * 2];
    float4 b = reinterpret_cast<const float4*>(x)[i * 2 + 1];
    uint4 p = { pack2(a.x, a.y), pack2(a.z, a.w), pack2(b.x, b.y), pack2(b.z, b.w) };
    reinterpret_cast<uint4*>(xb)[i] = p;
}

// ---------------------------------------------------------------------------
// pre3[d][b][l][n'] (bf16, b-major), n' = col*4+gate, scaled by LOG2E.
// m97-style: 128x128 tile, BK=32, global_load_lds(16B). M-tile = one b, 128 l.
// ---------------------------------------------------------------------------
__global__ __launch_bounds__(256) void pre_gemm(
    const unsigned short* __restrict__ xb,    // (B,L,E) bf16
    const unsigned short* __restrict__ wp,    // (2048,512) bf16 permuted*LOG2E
    const float* __restrict__ bias_p,         // (2048) permuted*LOG2E
    unsigned short* __restrict__ pre3)        // [2][128][512][1024]
{
    __shared__ unsigned short A_lds[128 * 32];   // [row][k], 64B/row (no pad: DMA linear)
    __shared__ unsigned short B_lds[128 * 32];

    int nt = blockIdx.x, mt = blockIdx.y;
    int tid = threadIdx.x;
    int n0 = nt * 128;
    int b  = mt >> 2, l0 = (mt & 3) * 128;
    int w = tid >> 6, lane = tid & 63;
    int q = lane >> 4, ln = lane & 15;
    int wm = (w >> 1) * 64, wn = (w & 1) * 64;

    f32x4 acc[4][4];
    #pragma unroll
    for (int i = 0; i < 4; ++i)
        #pragma unroll
        for (int j = 0; j < 4; ++j) acc[i][j] = (f32x4){0.f, 0.f, 0.f, 0.f};

    int r_ = tid >> 2, kp = (tid & 3) * 8;
    const unsigned short* asrc0 = xb + ((size_t)b * 512 + l0 + r_) * 512 + kp;
    const unsigned short* asrc1 = asrc0 + (size_t)64 * 512;
    const unsigned short* bsrc0 = wp + (size_t)(n0 + r_) * 512 + kp;
    const unsigned short* bsrc1 = bsrc0 + (size_t)64 * 512;
    unsigned short* adst0 = &A_lds[tid * 8];
    unsigned short* adst1 = &A_lds[2048 + tid * 8];
    unsigned short* bdst0 = &B_lds[tid * 8];
    unsigned short* bdst1 = &B_lds[2048 + tid * 8];

    for (int kc = 0; kc < 16; ++kc) {
        int k0 = kc * 32;
        gl_lds16(asrc0 + k0, adst0);
        gl_lds16(asrc1 + k0, adst1);
        gl_lds16(bsrc0 + k0, bdst0);
        gl_lds16(bsrc1 + k0, bdst1);
        __syncthreads();   // drains vmcnt -> LDS filled

        bf16x8 af[4], bfv[4];
        #pragma unroll
        for (int ms = 0; ms < 4; ++ms)
            af[ms] = *reinterpret_cast<const bf16x8*>(&A_lds[(wm + ms * 16 + ln) * 32 + q * 8]);
        #pragma unroll
        for (int ns = 0; ns < 4; ++ns)
            bfv[ns] = *reinterpret_cast<const bf16x8*>(&B_lds[(wn + ns * 16 + ln) * 32 + q * 8]);
        #pragma unroll
        for (int ms = 0; ms < 4; ++ms)
            #pragma unroll
            for (int ns = 0; ns < 4; ++ns)
                acc[ms][ns] = __builtin_amdgcn_mfma_f32_16x16x32_bf16(af[ms], bfv[ns], acc[ms][ns], 0, 0, 0);
        __syncthreads();   // frag reads done before next DMA overwrites
    }

    #pragma unroll
    for (int ns = 0; ns < 4; ++ns) {
        int n = n0 + wn + ns * 16 + ln;
        float bias = bias_p[n];
        int dsel = n >> 10, np = n & 1023;
        #pragma unroll
        for (int ms = 0; ms < 4; ++ms) {
            #pragma unroll
            for (int rg = 0; rg < 4; ++rg) {
                int l = l0 + wm + ms * 16 + q * 4 + rg;
                pre3[(((size_t)dsel * 128 + b) * 512 + l) * 1024 + np] = f2bf(acc[ms][ns][rg] + bias);
            }
        }
    }
}

// ---------------------------------------------------------------------------
// LSTM scan v8 = v6 structure (256 WGs, one (d,b) per WG, verified @446us)
// + raw barrier (lgkmcnt(0) only -> hcat stores and pre3 prefetch loads stay
//   in flight across the step barrier instead of draining vmcnt(0) each step)
// + s_setprio(1) around the MFMA cluster.
// MX fp8 MFMA 16x16x128 (M=16 tile, valid row 0), W_hh register-resident.
// Valid G row sits in acc[g][s][0] of lanes 0-15 (q=0). 8 __shfl + selects
// put all 4 gates of col (w+8*(lane>>4))*16+(lane&15) into lanes 0-31 of the
// SAME wave -> in-register activation -> fp8 h byte to h_lds row 0 + bf16
// hcat. ONE barrier per step.
// ---------------------------------------------------------------------------
__global__ __launch_bounds__(512, 2) void lstm_scan(
    const unsigned short* __restrict__ pre3,  // [2][128][512][1024] bf16 (scaled)
    const unsigned char* __restrict__ whh8,   // [2][1024][256] fp8 e4m3 (scaled)
    unsigned short* __restrict__ hcat)        // [512][128][512] bf16
{
    __shared__ unsigned char h_lds[2][16 * 272];   // fp8; rows 1..15 stay 0 forever

    int wg = blockIdx.x;           // 256 = 2 dirs x 128 batch
    int d = wg >> 7, b = wg & 127;
    int tid = threadIdx.x, w = tid >> 6, lane = tid & 63;
    int q = lane >> 4, ln = lane & 15;

    const unsigned char* whh_d = whh8 + (size_t)d * (1024 * 256);
    const unsigned short* pre_wg = pre3 + ((size_t)d * 128 + b) * (512 * 1024);

    // W_hh B-frags: tile T = g*16 + (w+8s); B[n=T*16+ln][k=kc*128+q*32+j]
    i32x8 wh[4][2][2];
    #pragma unroll
    for (int g = 0; g < 4; ++g)
        #pragma unroll
        for (int s = 0; s < 2; ++s) {
            int row = g * 256 + (w + 8 * s) * 16 + ln;
            #pragma unroll
            for (int kc = 0; kc < 2; ++kc)
                wh[g][s][kc] = *reinterpret_cast<const i32x8*>(
                    whh_d + (size_t)row * 256 + kc * 128 + q * 32);
        }

    for (int i = tid; i < (2 * 16 * 272) / 4; i += 512) ((int*)h_lds)[i] = 0;

    // activation mapping: lanes 0-31 of each wave own col = (w+8*s)*16+ln
    bool act = (lane < 32);
    int s_  = (lane >> 4) & 1;
    int col = (w + 8 * s_) * 16 + ln;

    ushort4 p0 = {0,0,0,0}, p1 = {0,0,0,0};
    if (act) {
        int la  = (d == 0) ? 0 : (L_ - 1);
        int lb_ = (d == 0) ? 1 : (L_ - 2);
        p0 = *reinterpret_cast<const ushort4*>(pre_wg + (size_t)la * 1024 + col * 4);
        p1 = *reinterpret_cast<const ushort4*>(pre_wg + (size_t)lb_ * 1024 + col * 4);
    }
    __syncthreads();

    float cst = 0.f;

    for (int t = 0; t < L_; ++t) {
        int p = t & 1;
        int l = (d == 0) ? t : (L_ - 1 - t);

        // prefetch pre[t+2] (stays in flight across the raw barrier)
        ushort4 p2 = {0,0,0,0};
        if (act) {
            int t2 = (t + 2 < L_) ? (t + 2) : (L_ - 1);
            int l2 = (d == 0) ? t2 : (L_ - 1 - t2);
            p2 = *reinterpret_cast<const ushort4*>(pre_wg + (size_t)l2 * 1024 + col * 4);
        }

        // ---- MFMA: G = h @ W_hh^T (MX fp8, K=256 = 2 chunks of 128) ----
        f32x4 acc[4][2];
        #pragma unroll
        for (int g = 0; g < 4; ++g) {
            acc[g][0] = (f32x4){0.f, 0.f, 0.f, 0.f};
            acc[g][1] = (f32x4){0.f, 0.f, 0.f, 0.f};
        }
        __builtin_amdgcn_s_setprio(1);
        #pragma unroll
        for (int kc = 0; kc < 2; ++kc) {
            const unsigned char* ab = &h_lds[p][ln * 272 + kc * 128 + q * 32];
            uint4 a0 = *reinterpret_cast<const uint4*>(ab);
            uint4 a1 = *reinterpret_cast<const uint4*>(ab + 16);
            i32x8 af = { (int)a0.x, (int)a0.y, (int)a0.z, (int)a0.w,
                         (int)a1.x, (int)a1.y, (int)a1.z, (int)a1.w };
            #pragma unroll
            for (int g = 0; g < 4; ++g)
                #pragma unroll
                for (int s = 0; s < 2; ++s)
                    acc[g][s] = __builtin_amdgcn_mfma_scale_f32_16x16x128_f8f6f4(
                        af, wh[g][s][kc], acc[g][s], 0, 0,
                        0, 0x7f7f7f7f, 0, 0x7f7f7f7f);
        }
        __builtin_amdgcn_s_setprio(0);

        // ---- in-register redistribution: lane<32 gets its col's 4 gates ----
        float gv[4];
        #pragma unroll
        for (int g = 0; g < 4; ++g) {
            float lo = __shfl(acc[g][0][0], ln);   // from q=0 holder lane ln
            float hi = __shfl(acc[g][1][0], ln);
            gv[g] = s_ ? hi : lo;
        }

        // ---- activation on lanes 0-31 (1 unit each) ----
        if (act) {
            float vi = gv[0] + bf2f(p0.x);
            float vf = gv[1] + bf2f(p0.y);
            float vg = gv[2] + bf2f(p0.z);
            float vo = gv[3] + bf2f(p0.w);
            float ei  = ex2(vi);
            float e2g = ex2(vg + vg);
            float itg = (ei * (e2g - 1.f)) * rcp_((1.f + ei) * (1.f + e2g));  // sigm(i)*tanh(g)
            float sf  = rcp_(1.f + ex2(-vf));
            float cn  = fmaf(sf, cst, itg);
            cst = cn;
            float tc  = fmaf(-2.f, rcp_(1.f + ex2((2.f * LOG2E) * cn)), 1.f); // tanh(c)
            float so  = rcp_(1.f + ex2(-vo));
            float hn  = so * tc;
            int pk = __builtin_amdgcn_cvt_pk_fp8_f32(hn, hn, 0, false);
            h_lds[p ^ 1][col] = (unsigned char)(pk & 0xff);
            hcat[((size_t)l * 128 + b) * 512 + d * 256 + col] = f2bf(hn);
        }
        // raw barrier: only drain LDS (h_lds[p^1] writes); global store/load
        // stay in flight (compiler inserts counted vmcnt at their uses).
        asm volatile("s_waitcnt lgkmcnt(0)" ::: "memory");
        __builtin_amdgcn_s_barrier();

        p0 = p1; p1 = p2;
    }
}

// ---------------------------------------------------------------------------
// emit[b][l][k] = hcat[l][b][:] . w_emit[k][:] + b_emit[k]   (fp32 out)
// ---------------------------------------------------------------------------
__global__ __launch_bounds__(256) void emit_gemm(
    const unsigned short* __restrict__ hcat,   // [L*B][512]
    const unsigned short* __restrict__ wemit,  // [64][512]
    const float* __restrict__ bemit,           // [64]
    float* __restrict__ emit)                  // [B][L][64]
{
    int m0 = blockIdx.x * 64;
    int tid = threadIdx.x, w = tid >> 6, lane = tid & 63;
    int quad = lane >> 4, ln = lane & 15;
    int mrow = m0 + w * 16;

    f32x4 acc[4];
    #pragma unroll
    for (int i = 0; i < 4; ++i) acc[i] = (f32x4){0.f, 0.f, 0.f, 0.f};

    const unsigned short* arow = hcat + (size_t)(mrow + ln) * 512;
    #pragma unroll 4
    for (int kc = 0; kc < 16; ++kc) {
        bf16x8 af = *reinterpret_cast<const bf16x8*>(arow + kc * 32 + quad * 8);
        #pragma unroll
        for (int T = 0; T < 4; ++T) {
            bf16x8 bfv = *reinterpret_cast<const bf16x8*>(wemit + (size_t)(T * 16 + ln) * 512 + kc * 32 + quad * 8);
            acc[T] = __builtin_amdgcn_mfma_f32_16x16x32_bf16(af, bfv, acc[T], 0, 0, 0);
        }
    }
    #pragma unroll
    for (int T = 0; T < 4; ++T) {
        int k = T * 16 + ln;
        float bias = bemit[k];
        #pragma unroll
        for (int rg = 0; rg < 4; ++rg) {
            int m = mrow + quad * 4 + rg;
            int ll = m >> 7, bidx = m & 127;
            emit[((size_t)bidx * L_ + ll) * K_ + k] = acc[T][rg] + bias;
        }
    }
}

// ---------------------------------------------------------------------------
// CRF: per batch row (one wave), 511 sequential steps.
// v8: single-wave WG -> no s_barrier needed at all; replace __syncthreads
// (which drained the enext global prefetch every step via vmcnt(0)) with a
// pure lgkmcnt(0) wait. 4 independent fma accumulators; double-buffered els.
// ---------------------------------------------------------------------------
__global__ __launch_bounds__(64) void crf_kernel(
    const float* __restrict__ emit,    // [B][L][64]
    const int* __restrict__ labels,    // [B][L]
    const float* __restrict__ trans,   // [64][64]
    float* __restrict__ out)           // [B]
{
    __shared__ float els[2][64];
    int b = blockIdx.x, lane = threadIdx.x;
    const float* eb = emit + (size_t)b * L_ * K_;
    const int* lb = labels + (size_t)b * L_;

    float gold = 0.f;
    for (int t = lane; t < L_; t += 64) gold += eb[(size_t)t * K_ + lb[t]];
    for (int t = lane; t < L_ - 1; t += 64) gold += trans[lb[t] * K_ + lb[t + 1]];
    #pragma unroll
    for (int off = 32; off; off >>= 1) gold += __shfl_down(gold, off);

    float expT[64];   // column `lane` of exp(T)
    #pragma unroll
    for (int i = 0; i < 64; ++i) expT[i] = __expf(trans[i * K_ + lane]);

    float dstate = eb[lane];
    float enext = eb[K_ + lane];
    for (int t = 1; t < L_; ++t) {
        float ecur = enext;
        if (t + 1 < L_) enext = eb[(size_t)(t + 1) * K_ + lane];
        float M = __builtin_amdgcn_readfirstlane(dstate);   // cheap shared shift
        float e = __expf(dstate - M);
        float* el = els[t & 1];
        el[lane] = e;
        // single wave: LDS write visibility needs only lgkmcnt(0), no barrier,
        // and crucially no vmcnt(0) drain of the enext prefetch.
        asm volatile("s_waitcnt lgkmcnt(0)" ::: "memory");
        float s0 = 0.f, s1 = 0.f, s2 = 0.f, s3 = 0.f;
        #pragma unroll
        for (int i = 0; i < 64; i += 16) {
            float4 a0 = *reinterpret_cast<const float4*>(&el[i]);
            float4 a1 = *reinterpret_cast<const float4*>(&el[i + 4]);
            float4 a2 = *reinterpret_cast<const float4*>(&el[i + 8]);
            float4 a3 = *reinterpret_cast<const float4*>(&el[i + 12]);
            s0 = fmaf(a0.x, expT[i], s0);      s0 = fmaf(a0.y, expT[i + 1], s0);
            s0 = fmaf(a0.z, expT[i + 2], s0);  s0 = fmaf(a0.w, expT[i + 3], s0);
            s1 = fmaf(a1.x, expT[i + 4], s1);  s1 = fmaf(a1.y, expT[i + 5], s1);
            s1 = fmaf(a1.z, expT[i + 6], s1);  s1 = fmaf(a1.w, expT[i + 7], s1);
            s2 = fmaf(a2.x, expT[i + 8], s2);  s2 = fmaf(a2.y, expT[i + 9], s2);
            s2 = fmaf(a2.z, expT[i + 10], s2); s2 = fmaf(a2.w, expT[i + 11], s2);
            s3 = fmaf(a3.x, expT[i + 12], s3); s3 = fmaf(a3.y, expT[i + 13], s3);
            s3 = fmaf(a3.z, expT[i + 14], s3); s3 = fmaf(a3.w, expT[i + 15], s3);
        }
        dstate = M + __logf((s0 + s1) + (s2 + s3)) + ecur;
    }
    float M = __builtin_amdgcn_readfirstlane(dstate);
    float e = __expf(dstate - M);
    float s = e;
    #pragma unroll
    for (int off = 32; off; off >>= 1) s += __shfl_xor(s, off);
    float logZ = M + __logf(s);
    if (lane == 0) out[b] = -(gold - logZ);
}

// ---------------------------------------------------------------------------
// Workspace layout (bytes). Overlays (disjoint lifetimes):
//   xb aliases hcat; emit aliases pre3 head.
// ---------------------------------------------------------------------------
#define OFF_PRE    ((size_t)0)                        // 268435456
#define OFF_EMIT   OFF_PRE                            // 16777216 (alias)
#define OFF_HCAT   ((size_t)268435456)                // 67108864
#define OFF_XB     OFF_HCAT                           // 67108864 (alias)
#define OFF_WHH8   ((size_t)(OFF_HCAT + 67108864))    // 524288
#define OFF_WEMIT  ((size_t)(OFF_WHH8 + 524288))      // 65536
#define OFF_WP     ((size_t)(OFF_WEMIT + 65536))      // 2097152
#define OFF_BIAS   ((size_t)(OFF_WP + 2097152))       // 8192

extern "C" void kernel_launch(void* const* d_in, const int* in_sizes, int n_in,
                              void* d_out, int out_size, void* d_ws, size_t ws_size,
                              hipStream_t stream) {
    const float* x      = (const float*)d_in[0];
    const int*   labels = (const int*)d_in[1];
    const float* wihf   = (const float*)d_in[2];
    const float* whhf   = (const float*)d_in[3];
    const float* bihf   = (const float*)d_in[4];
    const float* bhhf   = (const float*)d_in[5];
    const float* wihb   = (const float*)d_in[6];
    const float* whhb   = (const float*)d_in[7];
    const float* bihb   = (const float*)d_in[8];
    const float* bhhb   = (const float*)d_in[9];
    const float* wemit  = (const float*)d_in[10];
    const float* bemit  = (const float*)d_in[11];
    const float* trans  = (const float*)d_in[12];
    float* out = (float*)d_out;

    char* ws = (char*)d_ws;
    unsigned short* pre3   = (unsigned short*)(ws + OFF_PRE);
    unsigned short* hcat   = (unsigned short*)(ws + OFF_HCAT);
    unsigned short* xb     = (unsigned short*)(ws + OFF_XB);
    float*          emit   = (float*)(ws + OFF_EMIT);
    unsigned char*  whh8   = (unsigned char*)(ws + OFF_WHH8);
    unsigned short* we_bf  = (unsigned short*)(ws + OFF_WEMIT);
    unsigned short* wp     = (unsigned short*)(ws + OFF_WP);
    float*          bias_p = (float*)(ws + OFF_BIAS);

    setup_convert<<<1024, 256, 0, stream>>>(whhf, whhb, wemit, wihf, wihb,
                                            bihf, bhhf, bihb, bhhb,
                                            whh8, we_bf, wp, bias_p);
    convert_x<<<16384, 256, 0, stream>>>(x, xb);
    pre_gemm<<<dim3(16, 512), 256, 0, stream>>>(xb, wp, bias_p, pre3);
    lstm_scan<<<256, 512, 0, stream>>>(pre3, whh8, hcat);
    emit_gemm<<<1024, 256, 0, stream>>>(hcat, we_bf, bemit, emit);
    crf_kernel<<<128, 64, 0, stream>>>(emit, labels, trans, out);
}